// Round 3
// baseline (1194.767 us; speedup 1.0000x reference)
//
#include <hip/hip_runtime.h>
#include <hip/hip_bf16.h>

#define U_CNT 339
#define S_CNT 5825
#define N_CNT 6164          // U + S
#define D_DIM 128
#define R_DIM 32
#define B_CNT 500000
#define M_EDGE 400000       // 2*NNZ (symmetrized)
#define H_DIM 64
#define LN_EPS 1e-5f

typedef __hip_bfloat16 bf16;

__device__ __forceinline__ float b2f(bf16 x) { return __bfloat162float(x); }

// generic float-input load: isf32 selects fp32 vs bf16 interpretation
__device__ __forceinline__ float ldf(const void* p, long i, int isf32) {
    return isf32 ? ((const float*)p)[i] : b2f(((const bf16*)p)[i]);
}

// ---------- dtype detector: 1 wave, inspects uEmbeds as bf16 pairs ----------
__global__ void k_detect(const void* __restrict__ uE, int* __restrict__ flag) {
    const unsigned short* p = (const unsigned short*)uE;
    int j = threadIdx.x;                      // 0..63
    unsigned short v = p[2 * j];              // even bf16 element
    int e = (v >> 7) & 0xFF;                  // bf16 exponent field
    int bad = (e >= 127);                     // |x|>=1 or NaN/Inf: impossible for Xavier bf16
    unsigned long long m = __ballot(bad != 0);
    if (j == 0) flag[0] = (m != 0ull) ? 1 : 0;   // 1 => buffers are fp32
}

// ---------- zero two int arrays of length N_CNT ----------
__global__ void k_zero2(int* __restrict__ a, int* __restrict__ b) {
    int i = blockIdx.x * 256 + threadIdx.x;
    if (i < N_CNT) { a[i] = 0; b[i] = 0; }
}

// ---------- cast + concat embeddings to fp32 [N, D] ----------
__global__ void k_concat(const void* __restrict__ uE, const void* __restrict__ iE,
                         float* __restrict__ E, const int* __restrict__ flag) {
    int isf32 = flag[0];
    int i = blockIdx.x * 256 + threadIdx.x;          // grid sized exactly
    const int uTot = U_CNT * D_DIM;
    E[i] = (i < uTot) ? ldf(uE, i, isf32) : ldf(iE, i - uTot, isf32);
}

// ---------- CSR build: histogram ----------
__global__ void k_hist(const int* __restrict__ rows, int* __restrict__ counts) {
    int e = blockIdx.x * 256 + threadIdx.x;
    if (e < M_EDGE) atomicAdd(&counts[rows[e]], 1);
}

// ---------- CSR build: exclusive scan over N=6164 counts (one 256-thread block) ----------
__global__ void k_scan(const int* __restrict__ counts, int* __restrict__ row_ptr) {
    __shared__ int part[256];
    const int RPT = 25;                               // 256*25 = 6400 >= N+1
    int t = threadIdx.x;
    int base = t * RPT;
    int local[RPT];
    int s = 0;
    #pragma unroll
    for (int i = 0; i < RPT; ++i) {
        int idx = base + i;
        int v = (idx < N_CNT) ? counts[idx] : 0;
        local[i] = s;
        s += v;
    }
    part[t] = s;
    __syncthreads();
    for (int off = 1; off < 256; off <<= 1) {
        int v = (t >= off) ? part[t - off] : 0;
        __syncthreads();
        part[t] += v;
        __syncthreads();
    }
    int prefix = (t > 0) ? part[t - 1] : 0;
    #pragma unroll
    for (int i = 0; i < RPT; ++i) {
        int idx = base + i;
        if (idx <= N_CNT) row_ptr[idx] = prefix + local[i];
    }
}

// ---------- CSR build: scatter edges ----------
__global__ void k_scatter(const int* __restrict__ rows, const int* __restrict__ cols,
                          const void* __restrict__ vals, const int* __restrict__ row_ptr,
                          int* __restrict__ fill, int* __restrict__ csr_col,
                          float* __restrict__ csr_val, const int* __restrict__ flag) {
    int e = blockIdx.x * 256 + threadIdx.x;
    if (e >= M_EDGE) return;
    int isf32 = flag[0];
    int r = rows[e];
    int pos = atomicAdd(&fill[r], 1);
    int o = row_ptr[r] + pos;
    csr_col[o] = cols[e];
    csr_val[o] = ldf(vals, e, isf32);
}

// ---------- SpMM gather: Eout[r,:] = sum_k val[k] * Ein[col[k],:] ----------
__global__ void k_spmm(const float* __restrict__ Ein, float* __restrict__ Eout,
                       const int* __restrict__ row_ptr, const int* __restrict__ csr_col,
                       const float* __restrict__ csr_val) {
    int r = blockIdx.x;
    int d = threadIdx.x;
    int k0 = row_ptr[r], k1 = row_ptr[r + 1];
    float acc = 0.f;
    for (int k = k0; k < k1; ++k)
        acc = fmaf(csr_val[k], Ein[csr_col[k] * D_DIM + d], acc);
    Eout[r * D_DIM + d] = acc;
}

// ---------- P = Hyperᵀ (Hyper @ W1part)  [128 x 64] per side ----------
__global__ void k_hyperP(const void* __restrict__ uHy, const void* __restrict__ iHy,
                         const void* __restrict__ W1, float* __restrict__ P,
                         const int* __restrict__ flag) {
    int isf32 = flag[0];
    int side = blockIdx.x;                           // 0 = user, 1 = service
    const void* Hy = side ? iHy : uHy;               // [32][128]
    long wbase = (long)side * D_DIM * H_DIM;         // rows [side*128 .. +128) of W1
    __shared__ float Hs[R_DIM * D_DIM];              // 16 KB
    __shared__ float T[R_DIM * H_DIM];               // 8 KB: T = Hy @ Wpart [32 x 64]
    for (int idx = threadIdx.x; idx < R_DIM * D_DIM; idx += 256)
        Hs[idx] = ldf(Hy, idx, isf32);
    __syncthreads();
    for (int idx = threadIdx.x; idx < R_DIM * H_DIM; idx += 256) {
        int a = idx >> 6, j = idx & 63;
        float acc = 0.f;
        for (int d = 0; d < D_DIM; ++d)
            acc = fmaf(Hs[a * D_DIM + d], ldf(W1, wbase + d * H_DIM + j, isf32), acc);
        T[idx] = acc;
    }
    __syncthreads();
    for (int idx = threadIdx.x; idx < D_DIM * H_DIM; idx += 256) {
        int d = idx >> 6, j = idx & 63;
        float acc = 0.f;
        #pragma unroll
        for (int a = 0; a < R_DIM; ++a)
            acc = fmaf(Hs[a * D_DIM + d], T[a * H_DIM + j], acc);
        P[side * D_DIM * H_DIM + idx] = acc;
    }
}

// ---------- A[r,:] = E[r,:] @ P(side)   [N x 64] ----------
__global__ void k_A(const float* __restrict__ E, const float* __restrict__ P,
                    float* __restrict__ A) {
    int r = blockIdx.x;
    int j = threadIdx.x;                              // 64 threads
    const float* Pr = P + ((r < U_CNT) ? 0 : D_DIM * H_DIM);
    const float* Er = E + r * D_DIM;
    float acc = 0.f;
    #pragma unroll 8
    for (int d = 0; d < D_DIM; ++d)
        acc = fmaf(Er[d], Pr[d * H_DIM + j], acc);
    A[r * H_DIM + j] = acc;
}

// ---------- big fused MLP: wave-per-row, W2 column in VGPRs ----------
__global__ void __launch_bounds__(256)
HyperModel_65755949301857_kernel(
      const float* __restrict__ A, const int* __restrict__ userIdx,
      const int* __restrict__ servIdx, const void* __restrict__ W2,
      const void* __restrict__ b1, const void* __restrict__ g1, const void* __restrict__ be1,
      const void* __restrict__ b2, const void* __restrict__ g2, const void* __restrict__ be2,
      const void* __restrict__ W3, const void* __restrict__ b3, void* __restrict__ out,
      const int* __restrict__ flag) {
    int isf32 = flag[0];
    int wave = threadIdx.x >> 6;
    int j = threadIdx.x & 63;                         // feature index == lane
    float w2c[64];                                    // column j of W2 in registers
    #pragma unroll
    for (int k = 0; k < 64; ++k) w2c[k] = ldf(W2, k * H_DIM + j, isf32);
    float b1j = ldf(b1, j, isf32), g1j = ldf(g1, j, isf32), be1j = ldf(be1, j, isf32);
    float b2j = ldf(b2, j, isf32), g2j = ldf(g2, j, isf32), be2j = ldf(be2, j, isf32);
    float w3j = ldf(W3, j, isf32);
    float b3v = ldf(b3, 0, isf32);
    const float* As = A + U_CNT * H_DIM;
    int nwaves = gridDim.x * 4;
    for (int b = blockIdx.x * 4 + wave; b < B_CNT; b += nwaves) {
        int ui = userIdx[b];
        int si = servIdx[b];
        float z = A[ui * H_DIM + j] + As[si * H_DIM + j] + b1j;
        // LayerNorm 1 over 64 lanes
        float s1 = z, s2 = z * z;
        #pragma unroll
        for (int off = 32; off >= 1; off >>= 1) {
            s1 += __shfl_xor(s1, off, 64);
            s2 += __shfl_xor(s2, off, 64);
        }
        float mu = s1 * (1.f / 64.f);
        float var = s2 * (1.f / 64.f) - mu * mu;
        float rs = rsqrtf(var + LN_EPS);
        float h = fmaxf(fmaf((z - mu) * rs, g1j, be1j), 0.f);
        // y = h @ W2 + b2 via lane-broadcast
        float y = b2j;
        #pragma unroll
        for (int k = 0; k < 64; ++k)
            y = fmaf(__shfl(h, k, 64), w2c[k], y);
        // LayerNorm 2
        s1 = y; s2 = y * y;
        #pragma unroll
        for (int off = 32; off >= 1; off >>= 1) {
            s1 += __shfl_xor(s1, off, 64);
            s2 += __shfl_xor(s2, off, 64);
        }
        mu = s1 * (1.f / 64.f);
        var = s2 * (1.f / 64.f) - mu * mu;
        rs = rsqrtf(var + LN_EPS);
        float h2 = fmaxf(fmaf((y - mu) * rs, g2j, be2j), 0.f);
        // out = h2 @ W3 + b3
        float o = h2 * w3j;
        #pragma unroll
        for (int off = 32; off >= 1; off >>= 1) o += __shfl_xor(o, off, 64);
        if (j == 0) {
            float r = o + b3v;
            if (isf32) ((float*)out)[b] = r;
            else       ((bf16*)out)[b] = __float2bfloat16(r);
        }
    }
}

extern "C" __attribute__((visibility("default")))
void kernel_launch(void* const* d_in, const int* in_sizes, int n_in,
                   void* d_out, int out_size, void* d_ws, size_t ws_size,
                   hipStream_t stream) {
    const void* uE   = d_in[0];
    const void* iE   = d_in[1];
    const void* uHy  = d_in[2];
    const void* iHy  = d_in[3];
    const void* W1   = d_in[4];
    const void* b1   = d_in[5];
    const void* g1   = d_in[6];
    const void* be1  = d_in[7];
    const void* W2   = d_in[8];
    const void* b2   = d_in[9];
    const void* g2   = d_in[10];
    const void* be2  = d_in[11];
    const void* W3   = d_in[12];
    const void* b3   = d_in[13];
    const void* adj_vals = d_in[14];
    const int*  adj_rows = (const int*)d_in[15];
    const int*  adj_cols = (const int*)d_in[16];
    const int*  userIdx  = (const int*)d_in[17];
    const int*  servIdx  = (const int*)d_in[18];

    char* w = (char*)d_ws;
    size_t off = 0;
    auto alloc = [&](size_t bytes) -> char* {
        char* p = w + off;
        off += (bytes + 255) & ~(size_t)255;
        return p;
    };
    float* E0      = (float*)alloc((size_t)N_CNT * D_DIM * 4);
    float* E1      = (float*)alloc((size_t)N_CNT * D_DIM * 4);
    float* P       = (float*)alloc((size_t)2 * D_DIM * H_DIM * 4);
    float* A       = (float*)alloc((size_t)N_CNT * H_DIM * 4);
    float* csr_val = (float*)alloc((size_t)M_EDGE * 4);
    int*   csr_col = (int*)alloc((size_t)M_EDGE * 4);
    int*   row_ptr = (int*)alloc((size_t)(N_CNT + 1) * 4);
    int*   counts  = (int*)alloc((size_t)N_CNT * 4);
    int*   fill    = (int*)alloc((size_t)N_CNT * 4);
    int*   flag    = (int*)alloc(256);

    k_detect<<<1, 64, 0, stream>>>(uE, flag);
    k_zero2<<<(N_CNT + 255) / 256, 256, 0, stream>>>(counts, fill);
    k_concat<<<(N_CNT * D_DIM) / 256, 256, 0, stream>>>(uE, iE, E0, flag);
    k_hist<<<(M_EDGE + 255) / 256, 256, 0, stream>>>(adj_rows, counts);
    k_scan<<<1, 256, 0, stream>>>(counts, row_ptr);
    k_scatter<<<(M_EDGE + 255) / 256, 256, 0, stream>>>(adj_rows, adj_cols, adj_vals,
                                                        row_ptr, fill, csr_col, csr_val, flag);
    // 3 propagation hops: E0 -> E1 -> E0 -> E1
    k_spmm<<<N_CNT, D_DIM, 0, stream>>>(E0, E1, row_ptr, csr_col, csr_val);
    k_spmm<<<N_CNT, D_DIM, 0, stream>>>(E1, E0, row_ptr, csr_col, csr_val);
    k_spmm<<<N_CNT, D_DIM, 0, stream>>>(E0, E1, row_ptr, csr_col, csr_val);

    k_hyperP<<<2, 256, 0, stream>>>(uHy, iHy, W1, P, flag);
    k_A<<<N_CNT, H_DIM, 0, stream>>>(E1, P, A);

    HyperModel_65755949301857_kernel<<<2048, 256, 0, stream>>>(
        A, userIdx, servIdx, W2, b1, g1, be1, b2, g2, be2, W3, b3, d_out, flag);
}

// Round 4
// 580.012 us; speedup vs baseline: 2.0599x; 2.0599x over previous
//
#include <hip/hip_runtime.h>
#include <hip/hip_bf16.h>

#define U_CNT 339
#define S_CNT 5825
#define N_CNT 6164          // U + S
#define D_DIM 128
#define R_DIM 32
#define B_CNT 500000
#define M_EDGE 400000       // 2*NNZ (symmetrized)
#define H_DIM 64
#define LN_EPS 1e-5f

// fp32 weight-block offsets (elements)
#define WF_W2   0
#define WF_B1   4096
#define WF_G1   4160
#define WF_BE1  4224
#define WF_B2   4288
#define WF_G2   4352
#define WF_BE2  4416
#define WF_W3   4480
#define WF_B3   4544
#define WF_TOT  4545

typedef __hip_bfloat16 bf16;

__device__ __forceinline__ float b2f(bf16 x) { return __bfloat162float(x); }

// generic float-input load: isf32 selects fp32 vs bf16 interpretation
__device__ __forceinline__ float ldf(const void* p, long i, int isf32) {
    return isf32 ? ((const float*)p)[i] : b2f(((const bf16*)p)[i]);
}

// ---------- init: zero counts/fill + dtype detect (block 0, wave 0) ----------
__global__ void k_init(const void* __restrict__ uE, int* __restrict__ counts,
                       int* __restrict__ fill, int* __restrict__ flag) {
    int i = blockIdx.x * 256 + threadIdx.x;
    if (i < N_CNT) { counts[i] = 0; fill[i] = 0; }
    if (blockIdx.x == 0 && threadIdx.x < 64) {
        const unsigned short* p = (const unsigned short*)uE;
        unsigned short v = p[2 * threadIdx.x];       // even bf16 element
        int e = (v >> 7) & 0xFF;                     // bf16 exponent field
        unsigned long long m = __ballot(e >= 127);   // impossible for Xavier bf16
        if (threadIdx.x == 0) flag[0] = (m != 0ull) ? 1 : 0;  // 1 => fp32 buffers
    }
}

// ---------- concat embeddings to fp32 [N,D] + edge histogram (fused) ----------
__global__ void k_pre(const void* __restrict__ uE, const void* __restrict__ iE,
                      float* __restrict__ E, const int* __restrict__ rows,
                      int* __restrict__ counts, const int* __restrict__ flag) {
    int i = blockIdx.x * 256 + threadIdx.x;
    int isf32 = flag[0];
    const int T1 = N_CNT * D_DIM;
    if (i < T1) {
        const int uTot = U_CNT * D_DIM;
        E[i] = (i < uTot) ? ldf(uE, i, isf32) : ldf(iE, i - uTot, isf32);
    }
    if (i < M_EDGE) atomicAdd(&counts[rows[i]], 1);
}

// ---------- CSR build: exclusive scan over N=6164 counts (one 256-thread block) ----------
__global__ void k_scan(const int* __restrict__ counts, int* __restrict__ row_ptr) {
    __shared__ int part[256];
    const int RPT = 25;                               // 256*25 = 6400 >= N+1
    int t = threadIdx.x;
    int base = t * RPT;
    int local[RPT];
    int s = 0;
    #pragma unroll
    for (int i = 0; i < RPT; ++i) {
        int idx = base + i;
        int v = (idx < N_CNT) ? counts[idx] : 0;
        local[i] = s;
        s += v;
    }
    part[t] = s;
    __syncthreads();
    for (int off = 1; off < 256; off <<= 1) {
        int v = (t >= off) ? part[t - off] : 0;
        __syncthreads();
        part[t] += v;
        __syncthreads();
    }
    int prefix = (t > 0) ? part[t - 1] : 0;
    #pragma unroll
    for (int i = 0; i < RPT; ++i) {
        int idx = base + i;
        if (idx <= N_CNT) row_ptr[idx] = prefix + local[i];
    }
}

// ---------- CSR build: scatter edges ----------
__global__ void k_scatter(const int* __restrict__ rows, const int* __restrict__ cols,
                          const void* __restrict__ vals, const int* __restrict__ row_ptr,
                          int* __restrict__ fill, int* __restrict__ csr_col,
                          float* __restrict__ csr_val, const int* __restrict__ flag) {
    int e = blockIdx.x * 256 + threadIdx.x;
    if (e >= M_EDGE) return;
    int isf32 = flag[0];
    int r = rows[e];
    int pos = atomicAdd(&fill[r], 1);
    int o = row_ptr[r] + pos;
    csr_col[o] = cols[e];
    csr_val[o] = ldf(vals, e, isf32);
}

// ---------- SpMM gather, float2, unroll-4 with independent accumulators ----------
__global__ void k_spmm(const float2* __restrict__ Ein2, float2* __restrict__ Eout2,
                       const int* __restrict__ row_ptr, const int* __restrict__ csr_col,
                       const float* __restrict__ csr_val) {
    int r = blockIdx.x;
    int d = threadIdx.x;                              // 0..63, two dims per lane
    int k0 = row_ptr[r], k1 = row_ptr[r + 1];
    float ax0 = 0, ay0 = 0, ax1 = 0, ay1 = 0, ax2 = 0, ay2 = 0, ax3 = 0, ay3 = 0;
    int k = k0;
    for (; k + 4 <= k1; k += 4) {
        int c0 = csr_col[k], c1 = csr_col[k + 1], c2 = csr_col[k + 2], c3 = csr_col[k + 3];
        float v0 = csr_val[k], v1 = csr_val[k + 1], v2 = csr_val[k + 2], v3 = csr_val[k + 3];
        float2 e0 = Ein2[c0 * 64 + d], e1 = Ein2[c1 * 64 + d];
        float2 e2 = Ein2[c2 * 64 + d], e3 = Ein2[c3 * 64 + d];
        ax0 = fmaf(v0, e0.x, ax0); ay0 = fmaf(v0, e0.y, ay0);
        ax1 = fmaf(v1, e1.x, ax1); ay1 = fmaf(v1, e1.y, ay1);
        ax2 = fmaf(v2, e2.x, ax2); ay2 = fmaf(v2, e2.y, ay2);
        ax3 = fmaf(v3, e3.x, ax3); ay3 = fmaf(v3, e3.y, ay3);
    }
    for (; k < k1; ++k) {
        int c = csr_col[k];
        float v = csr_val[k];
        float2 e = Ein2[c * 64 + d];
        ax0 = fmaf(v, e.x, ax0); ay0 = fmaf(v, e.y, ay0);
    }
    float2 o;
    o.x = (ax0 + ax1) + (ax2 + ax3);
    o.y = (ay0 + ay1) + (ay2 + ay3);
    Eout2[r * 64 + d] = o;
}

// ---------- blocks 0,1: P = Hyperᵀ(Hyper @ W1part); block 2: weights→fp32 ----------
__global__ void k_hyperP(const void* __restrict__ uHy, const void* __restrict__ iHy,
                         const void* __restrict__ W1, const void* __restrict__ W2,
                         const void* __restrict__ b1, const void* __restrict__ g1,
                         const void* __restrict__ be1, const void* __restrict__ b2,
                         const void* __restrict__ g2, const void* __restrict__ be2,
                         const void* __restrict__ W3, const void* __restrict__ b3,
                         float* __restrict__ P, float* __restrict__ Wf,
                         const int* __restrict__ flag) {
    int isf32 = flag[0];
    if (blockIdx.x == 2) {                            // weight prep
        for (int i = threadIdx.x; i < WF_TOT; i += 256) {
            float v;
            if      (i < WF_B1)  v = ldf(W2,  i,           isf32);
            else if (i < WF_G1)  v = ldf(b1,  i - WF_B1,   isf32);
            else if (i < WF_BE1) v = ldf(g1,  i - WF_G1,   isf32);
            else if (i < WF_B2)  v = ldf(be1, i - WF_BE1,  isf32);
            else if (i < WF_G2)  v = ldf(b2,  i - WF_B2,   isf32);
            else if (i < WF_BE2) v = ldf(g2,  i - WF_G2,   isf32);
            else if (i < WF_W3)  v = ldf(be2, i - WF_BE2,  isf32);
            else if (i < WF_B3)  v = ldf(W3,  i - WF_W3,   isf32);
            else                 v = ldf(b3,  0,           isf32);
            Wf[i] = v;
        }
        return;
    }
    int side = blockIdx.x;                            // 0 = user, 1 = service
    const void* Hy = side ? iHy : uHy;                // [32][128]
    long wbase = (long)side * D_DIM * H_DIM;          // rows [side*128 .. +128) of W1
    __shared__ float Hs[R_DIM * D_DIM];               // 16 KB
    __shared__ float T[R_DIM * H_DIM];                // 8 KB
    for (int idx = threadIdx.x; idx < R_DIM * D_DIM; idx += 256)
        Hs[idx] = ldf(Hy, idx, isf32);
    __syncthreads();
    for (int idx = threadIdx.x; idx < R_DIM * H_DIM; idx += 256) {
        int a = idx >> 6, j = idx & 63;
        float acc = 0.f;
        for (int d = 0; d < D_DIM; ++d)
            acc = fmaf(Hs[a * D_DIM + d], ldf(W1, wbase + d * H_DIM + j, isf32), acc);
        T[idx] = acc;
    }
    __syncthreads();
    for (int idx = threadIdx.x; idx < D_DIM * H_DIM; idx += 256) {
        int d = idx >> 6, j = idx & 63;
        float acc = 0.f;
        #pragma unroll
        for (int a = 0; a < R_DIM; ++a)
            acc = fmaf(Hs[a * D_DIM + d], T[a * H_DIM + j], acc);
        P[side * D_DIM * H_DIM + idx] = acc;
    }
}

// ---------- A[r,:] = E[r,:] @ P(side) (+ b1 folded into user rows) ----------
__global__ void k_A(const float* __restrict__ E, const float* __restrict__ P,
                    const float* __restrict__ Wf, float* __restrict__ A) {
    int r = blockIdx.x;
    int j = threadIdx.x;                              // 64 threads
    const float* Pr = P + ((r < U_CNT) ? 0 : D_DIM * H_DIM);
    const float* Er = E + r * D_DIM;                  // wave-uniform -> scalar loads
    float acc = (r < U_CNT) ? Wf[WF_B1 + j] : 0.f;
    #pragma unroll 8
    for (int d = 0; d < D_DIM; ++d)
        acc = fmaf(Er[d], Pr[d * H_DIM + j], acc);
    A[r * H_DIM + j] = acc;
}

// ---------- fused MLP: ONE ROW PER THREAD, no cross-lane ops ----------
__global__ void __launch_bounds__(256)
HyperModel_65755949301857_kernel(
      const float* __restrict__ A, const int* __restrict__ userIdx,
      const int* __restrict__ servIdx, const float* __restrict__ Wf,
      void* __restrict__ out, const int* __restrict__ flag) {
    int b = blockIdx.x * 256 + threadIdx.x;
    if (b >= B_CNT) return;
    int isf32 = flag[0];
    int ui = userIdx[b];
    int si = servIdx[b] + U_CNT;
    const float4* A4 = (const float4*)A;

    // z = A_u[ui] + A_s[si]  (b1 pre-folded into A_u)
    float z[64];
    #pragma unroll
    for (int q = 0; q < 16; ++q) {
        float4 a = A4[ui * 16 + q];
        float4 s = A4[si * 16 + q];
        z[4 * q + 0] = a.x + s.x;
        z[4 * q + 1] = a.y + s.y;
        z[4 * q + 2] = a.z + s.z;
        z[4 * q + 3] = a.w + s.w;
    }
    // LayerNorm 1 (in-register tree sums)
    float s0 = 0, s1 = 0, s2 = 0, s3 = 0, q0 = 0, q1 = 0, q2 = 0, q3 = 0;
    #pragma unroll
    for (int k = 0; k < 64; k += 4) {
        s0 += z[k];     q0 = fmaf(z[k],     z[k],     q0);
        s1 += z[k + 1]; q1 = fmaf(z[k + 1], z[k + 1], q1);
        s2 += z[k + 2]; q2 = fmaf(z[k + 2], z[k + 2], q2);
        s3 += z[k + 3]; q3 = fmaf(z[k + 3], z[k + 3], q3);
    }
    float mu  = ((s0 + s1) + (s2 + s3)) * (1.f / 64.f);
    float ex2 = ((q0 + q1) + (q2 + q3)) * (1.f / 64.f);
    float rs = rsqrtf(ex2 - mu * mu + LN_EPS);
    float nmrs = -mu * rs;
    #pragma unroll
    for (int k = 0; k < 64; ++k) {
        float t = fmaf(z[k], rs, nmrs);
        z[k] = fmaxf(fmaf(t, Wf[WF_G1 + k], Wf[WF_BE1 + k]), 0.f);  // h, in place
    }
    // y = h @ W2 + b2 : W2 rows are wave-uniform -> scalar loads
    float y[64];
    #pragma unroll
    for (int j = 0; j < 64; ++j) y[j] = Wf[WF_B2 + j];
    #pragma unroll
    for (int k = 0; k < 64; ++k) {
        float hk = z[k];
        const float* wr = Wf + WF_W2 + k * 64;
        #pragma unroll
        for (int j = 0; j < 64; ++j) y[j] = fmaf(hk, wr[j], y[j]);
    }
    // LayerNorm 2 + relu + W3 dot
    s0 = s1 = s2 = s3 = q0 = q1 = q2 = q3 = 0;
    #pragma unroll
    for (int j = 0; j < 64; j += 4) {
        s0 += y[j];     q0 = fmaf(y[j],     y[j],     q0);
        s1 += y[j + 1]; q1 = fmaf(y[j + 1], y[j + 1], q1);
        s2 += y[j + 2]; q2 = fmaf(y[j + 2], y[j + 2], q2);
        s3 += y[j + 3]; q3 = fmaf(y[j + 3], y[j + 3], q3);
    }
    mu  = ((s0 + s1) + (s2 + s3)) * (1.f / 64.f);
    ex2 = ((q0 + q1) + (q2 + q3)) * (1.f / 64.f);
    float rs2 = rsqrtf(ex2 - mu * mu + LN_EPS);
    float nmrs2 = -mu * rs2;
    float o0 = 0, o1 = 0, o2 = 0, o3 = 0;
    #pragma unroll
    for (int j = 0; j < 64; j += 4) {
        float t0 = fmaxf(fmaf(fmaf(y[j],     rs2, nmrs2), Wf[WF_G2 + j],     Wf[WF_BE2 + j]),     0.f);
        float t1 = fmaxf(fmaf(fmaf(y[j + 1], rs2, nmrs2), Wf[WF_G2 + j + 1], Wf[WF_BE2 + j + 1]), 0.f);
        float t2 = fmaxf(fmaf(fmaf(y[j + 2], rs2, nmrs2), Wf[WF_G2 + j + 2], Wf[WF_BE2 + j + 2]), 0.f);
        float t3 = fmaxf(fmaf(fmaf(y[j + 3], rs2, nmrs2), Wf[WF_G2 + j + 3], Wf[WF_BE2 + j + 3]), 0.f);
        o0 = fmaf(t0, Wf[WF_W3 + j],     o0);
        o1 = fmaf(t1, Wf[WF_W3 + j + 1], o1);
        o2 = fmaf(t2, Wf[WF_W3 + j + 2], o2);
        o3 = fmaf(t3, Wf[WF_W3 + j + 3], o3);
    }
    float o = ((o0 + o1) + (o2 + o3)) + Wf[WF_B3];
    if (isf32) ((float*)out)[b] = o;
    else       ((bf16*)out)[b] = __float2bfloat16(o);
}

extern "C" __attribute__((visibility("default")))
void kernel_launch(void* const* d_in, const int* in_sizes, int n_in,
                   void* d_out, int out_size, void* d_ws, size_t ws_size,
                   hipStream_t stream) {
    const void* uE   = d_in[0];
    const void* iE   = d_in[1];
    const void* uHy  = d_in[2];
    const void* iHy  = d_in[3];
    const void* W1   = d_in[4];
    const void* b1   = d_in[5];
    const void* g1   = d_in[6];
    const void* be1  = d_in[7];
    const void* W2   = d_in[8];
    const void* b2   = d_in[9];
    const void* g2   = d_in[10];
    const void* be2  = d_in[11];
    const void* W3   = d_in[12];
    const void* b3   = d_in[13];
    const void* adj_vals = d_in[14];
    const int*  adj_rows = (const int*)d_in[15];
    const int*  adj_cols = (const int*)d_in[16];
    const int*  userIdx  = (const int*)d_in[17];
    const int*  servIdx  = (const int*)d_in[18];

    char* w = (char*)d_ws;
    size_t off = 0;
    auto alloc = [&](size_t bytes) -> char* {
        char* p = w + off;
        off += (bytes + 255) & ~(size_t)255;
        return p;
    };
    float* E0      = (float*)alloc((size_t)N_CNT * D_DIM * 4);
    float* E1      = (float*)alloc((size_t)N_CNT * D_DIM * 4);
    float* P       = (float*)alloc((size_t)2 * D_DIM * H_DIM * 4);
    float* A       = (float*)alloc((size_t)N_CNT * H_DIM * 4);
    float* csr_val = (float*)alloc((size_t)M_EDGE * 4);
    int*   csr_col = (int*)alloc((size_t)M_EDGE * 4);
    int*   row_ptr = (int*)alloc((size_t)(N_CNT + 1) * 4);
    int*   counts  = (int*)alloc((size_t)N_CNT * 4);
    int*   fill    = (int*)alloc((size_t)N_CNT * 4);
    int*   flag    = (int*)alloc(256);
    float* Wf      = (float*)alloc((size_t)WF_TOT * 4);

    k_init<<<(N_CNT + 255) / 256, 256, 0, stream>>>(uE, counts, fill, flag);
    k_pre<<<(N_CNT * D_DIM + 255) / 256, 256, 0, stream>>>(uE, iE, E0, adj_rows, counts, flag);
    k_scan<<<1, 256, 0, stream>>>(counts, row_ptr);
    k_scatter<<<(M_EDGE + 255) / 256, 256, 0, stream>>>(adj_rows, adj_cols, adj_vals,
                                                        row_ptr, fill, csr_col, csr_val, flag);
    // 3 propagation hops: E0 -> E1 -> E0 -> E1
    k_spmm<<<N_CNT, 64, 0, stream>>>((const float2*)E0, (float2*)E1, row_ptr, csr_col, csr_val);
    k_spmm<<<N_CNT, 64, 0, stream>>>((const float2*)E1, (float2*)E0, row_ptr, csr_col, csr_val);
    k_spmm<<<N_CNT, 64, 0, stream>>>((const float2*)E0, (float2*)E1, row_ptr, csr_col, csr_val);

    k_hyperP<<<3, 256, 0, stream>>>(uHy, iHy, W1, W2, b1, g1, be1, b2, g2, be2, W3, b3,
                                    P, Wf, flag);
    k_A<<<N_CNT, H_DIM, 0, stream>>>(E1, P, Wf, A);

    HyperModel_65755949301857_kernel<<<(B_CNT + 255) / 256, 256, 0, stream>>>(
        A, userIdx, servIdx, Wf, d_out, flag);
}